// Round 11
// baseline (109.192 us; speedup 1.0000x reference)
//
#include <hip/hip_runtime.h>

// Rotated NMS, N boxes [xc,yc,w,h,theta_deg], scores. Output: first 1000 kept
// original indices in score-sorted order, -1 padded. IoU math replicates the
// reference's float32 op order (contract off) — rounds 1-10: absmax 0.
//
// Round 11: (1) corners precomputed in K1 (kills per-survivor sincos +
// boxes-gather in K2); (2) sweep merged into K2 via last-block-done pattern
// (3 launches -> 2); r8 lesson: grid.sync is ~30us, but a single last-block
// handoff is one fence+atomic per block.

#define WL_LDS_CAP 4096
#define WL_G_CAP 65536
#define CF_T 256
#define CF_B 512

// ---------------- K1: rank + order + geo + corners (+ init) ---------------
__device__ __forceinline__ void make_corners(const float* __restrict__ bp,
                                             float* __restrict__ cr) {
#pragma clang fp contract(off)
  float xc = bp[0], yc = bp[1], w = bp[2], h = bp[3], th = bp[4];
  float ang = th * 0.017453292519943295f;
  float c = cosf(ang), sn = sinf(ang);
  float dx = w * 0.5f, dy = h * 0.5f;
  const float lx[4] = {-dx, dx, dx, -dx};
  const float ly[4] = {-dy, -dy, dy, dy};
#pragma unroll
  for (int k = 0; k < 4; ++k) {
    cr[2 * k] = xc + lx[k] * c - ly[k] * sn;  // no FMA: match reference
    cr[2 * k + 1] = yc + lx[k] * sn + ly[k] * c;
  }
}

__global__ void __launch_bounds__(256) rank_order(
    const float* __restrict__ boxes, const float* __restrict__ scores,
    int* __restrict__ order, float4* __restrict__ geo,
    float* __restrict__ corners, unsigned long long* __restrict__ mask,
    int words, int* __restrict__ wl_count, int* __restrict__ done, int N) {
#pragma clang fp contract(off)
  __shared__ float s[2048];
  int t = threadIdx.x;
  int gtid = blockIdx.x * 256 + t;
  if (gtid == 0) {
    *wl_count = 0;
    *done = 0;
  }
  size_t mtot = (size_t)N * words;
  for (size_t k = gtid; k < mtot; k += (size_t)gridDim.x * 256) mask[k] = 0ull;
  for (int k = t; k < N; k += 256) s[k] = scores[k];
  __syncthreads();
  int il = t >> 5, jc = t & 31;
  int i = blockIdx.x * 8 + il;
  int r = 0;
  if (i < N) {
    float si = s[i];
#pragma unroll 8
    for (int j = jc; j < N; j += 32) {
      float a = s[j];
      r += (a > si) || (a == si && j < i);
    }
  }
  r += __shfl_xor(r, 1);
  r += __shfl_xor(r, 2);
  r += __shfl_xor(r, 4);
  r += __shfl_xor(r, 8);
  r += __shfl_xor(r, 16);
  if (i < N && jc == 0) {
    order[r] = i;
    const float* bp = boxes + 5 * i;
    float w = bp[2], h = bp[3];
    float4 g;
    g.x = bp[0];
    g.y = bp[1];
    g.z = 0.5f * sqrtf(w * w + h * h);  // bounding-circle radius
    g.w = w * h;                        // area
    geo[r] = g;
    float cr[8];
    make_corners(bp, cr);
    float4* c4 = (float4*)(corners + 8 * r);
    c4[0] = make_float4(cr[0], cr[1], cr[2], cr[3]);
    c4[1] = make_float4(cr[4], cr[5], cr[6], cr[7]);
  }
}

// Exact SH clip, polygon in per-thread LDS slot (lane-major, conflict-free).
#define PIDX(bu, xy, v) ((((bu) * 2 + (xy)) * 8 + (v)) * CF_T + (t))
__device__ float clip_poly_lds(float* __restrict__ poly, int t,
                               const float* __restrict__ CA,
                               const float* __restrict__ CB) {
#pragma clang fp contract(off)
#pragma unroll
  for (int k = 0; k < 4; ++k) {
    poly[PIDX(0, 0, k)] = CA[2 * k];
    poly[PIDX(0, 1, k)] = CA[2 * k + 1];
  }
  int cnt = 4, cur = 0;
  for (int e = 0; e < 4; ++e) {
    float ax = CB[2 * e], ay = CB[2 * e + 1];
    int e2 = (e + 1) & 3;
    float bx = CB[2 * e2], by = CB[2 * e2 + 1];
    float ex = bx - ax, ey = by - ay;
    int nxtb = cur ^ 1;
    int ncnt = 0;
    for (int k = 0; k < cnt; ++k) {
      int kn = (k + 1 < cnt) ? k + 1 : 0;
      float px = poly[PIDX(cur, 0, k)], py = poly[PIDX(cur, 1, k)];
      float nx = poly[PIDX(cur, 0, kn)], ny = poly[PIDX(cur, 1, kn)];
      float dc = ex * (py - ay) - ey * (px - ax);
      float dn = ex * (ny - ay) - ey * (nx - ax);
      bool ic = (dc >= 0.0f), inx = (dn >= 0.0f);
      if (ic) {
        if (ncnt < 8) {
          poly[PIDX(nxtb, 0, ncnt)] = px;
          poly[PIDX(nxtb, 1, ncnt)] = py;
        }
        ++ncnt;
      }
      if (ic != inx) {
        float denom = dc - dn;
        float tp = (fabsf(denom) > 1e-12f) ? (dc / denom) : 0.0f;
        if (ncnt < 8) {
          poly[PIDX(nxtb, 0, ncnt)] = px + tp * (nx - px);
          poly[PIDX(nxtb, 1, ncnt)] = py + tp * (ny - py);
        }
        ++ncnt;
      }
    }
    cnt = ncnt > 8 ? 8 : ncnt;
    cur = nxtb;
  }
  float area = 0.0f;
  for (int k = 0; k < cnt; ++k) {
    int kn = (k + 1 < cnt) ? k + 1 : 0;
    area += poly[PIDX(cur, 0, k)] * poly[PIDX(cur, 1, kn)] -
            poly[PIDX(cur, 0, kn)] * poly[PIDX(cur, 1, k)];
  }
  return fmaxf(0.5f * area, 0.0f);
}

__device__ __forceinline__ void emit_pair(float inter, float ai, float aj,
                                          int i, int j,
                                          unsigned long long* __restrict__ mask,
                                          int words,
                                          unsigned int* __restrict__ wl,
                                          int* __restrict__ wl_count) {
#pragma clang fp contract(off)
  float uni = ai + aj - inter;
  float iou = inter / fmaxf(uni, 1e-9f);
  if (iou > 0.7f) {
    unsigned long long old =
        atomicOr(&mask[(size_t)i * words + (j >> 6)], 1ull << (j & 63));
    if (old == 0ull) {
      int x = atomicAdd(wl_count, 1);
      if (x < WL_G_CAP) wl[x] = ((unsigned)i << 6) | (unsigned)(j >> 6);
    }
  }
}

// -------- K2: prefilter + clip + (last block) greedy sweep + output -------
// LDS arena phase A: geoS 32K | buf 8K | poly 32K = 72K -> 2 blocks/CU.
// Phase B (last block only, aliased): h 8K | dst 8K | keys 16K | vals 32K |
// sup 512 | prefix | wtot.
__global__ void __launch_bounds__(CF_T) circle_clip_sweep(
    const float* __restrict__ corners, const int* __restrict__ order,
    const float4* __restrict__ geo, unsigned long long* __restrict__ mask,
    int words, unsigned int* __restrict__ wl, int* __restrict__ wl_count,
    int* __restrict__ done, int* __restrict__ out, int N, int topn) {
#pragma clang fp contract(off)
  __shared__ alignas(16) char arena[73728];
  __shared__ int bcnt, isLast;
  float4* geoS = (float4*)arena;                      // 32 KB
  unsigned int* buf = (unsigned int*)(arena + 32768);  // 8 KB
  float* poly = (float*)(arena + 40960);               // 32 KB
  int t = threadIdx.x;
  int lane = t & 63;
  int wid = t >> 6;
  if (t == 0) bcnt = 0;
  for (int k = t; k < N; k += CF_T) geoS[k] = geo[k];  // coalesced float4
  __syncthreads();

  int half = N >> 1;
  for (int rp = blockIdx.x; rp < half; rp += gridDim.x) {
    for (int q = 0; q < 2; ++q) {
      int i = q ? (N - 1 - rp) : rp;  // balanced row pair
      float4 gi = geoS[i];
      for (int j = i + 1 + t; j < N; j += CF_T) {
        float4 gj = geoS[j];
        float ddx = gj.x - gi.x, ddy = gj.y - gi.y;
        float rs = gi.z + gj.z;
        float mn = fminf(gi.w, gj.w), mx = fmaxf(gi.w, gj.w);
        // IoU <= min/(A+B-min): IoU>0.7 requires mn > 0.7*mx (0.699 margin)
        if (ddx * ddx + ddy * ddy <= rs * rs && mn > 0.699f * mx) {
          int idx = atomicAdd(&bcnt, 1);
          if (idx < 2048) {
            buf[idx] = ((unsigned)i << 16) | (unsigned)j;
          } else {  // overflow (adversarial only): inline clip
            float CA[8], CB[8];
            *(float4*)(CA) = ((const float4*)(corners + 8 * i))[0];
            *(float4*)(CA + 4) = ((const float4*)(corners + 8 * i))[1];
            *(float4*)(CB) = ((const float4*)(corners + 8 * j))[0];
            *(float4*)(CB + 4) = ((const float4*)(corners + 8 * j))[1];
            float inter = clip_poly_lds(poly, t, CA, CB);
            emit_pair(inter, gi.w, gj.w, i, j, mask, words, wl, wl_count);
          }
        }
      }
    }
  }
  if ((N & 1) && blockIdx.x == 0) {  // odd-N middle row
    int i = half;
    float4 gi = geoS[i];
    for (int j = i + 1 + t; j < N; j += CF_T) {
      float4 gj = geoS[j];
      float ddx = gj.x - gi.x, ddy = gj.y - gi.y;
      float rs = gi.z + gj.z;
      float mn = fminf(gi.w, gj.w), mx = fmaxf(gi.w, gj.w);
      if (ddx * ddx + ddy * ddy <= rs * rs && mn > 0.699f * mx) {
        int idx = atomicAdd(&bcnt, 1);
        if (idx < 2048) {
          buf[idx] = ((unsigned)i << 16) | (unsigned)j;
        } else {
          float CA[8], CB[8];
          *(float4*)(CA) = ((const float4*)(corners + 8 * i))[0];
          *(float4*)(CA + 4) = ((const float4*)(corners + 8 * i))[1];
          *(float4*)(CB) = ((const float4*)(corners + 8 * j))[0];
          *(float4*)(CB + 4) = ((const float4*)(corners + 8 * j))[1];
          float inter = clip_poly_lds(poly, t, CA, CB);
          emit_pair(inter, gi.w, gj.w, i, j, mask, words, wl, wl_count);
        }
      }
    }
  }
  __syncthreads();
  int n2 = bcnt < 2048 ? bcnt : 2048;
  for (int p = t; p < n2; p += CF_T) {
    unsigned int pk = buf[p];
    int i = pk >> 16, j = pk & 0xFFFF;
    float CA[8], CB[8];
    *(float4*)(CA) = ((const float4*)(corners + 8 * i))[0];
    *(float4*)(CA + 4) = ((const float4*)(corners + 8 * i))[1];
    *(float4*)(CB) = ((const float4*)(corners + 8 * j))[0];
    *(float4*)(CB + 4) = ((const float4*)(corners + 8 * j))[1];
    float inter = clip_poly_lds(poly, t, CA, CB);
    emit_pair(inter, geoS[i].w, geoS[j].w, i, j, mask, words, wl, wl_count);
  }

  // ---- last-block handoff (release/acquire via threadfence) ----
  __threadfence();
  __syncthreads();
  if (t == 0) isLast = (atomicAdd(done, 1) == (int)gridDim.x - 1);
  __syncthreads();
  if (!isLast) return;
  __threadfence();  // acquire: see all blocks' mask/wl writes

  // ---- greedy sweep (256 threads), LDS aliased over arena ----
  int* h = (int*)arena;                                   // 8 KB
  int* dst = (int*)(arena + 8192);                        // 8 KB
  unsigned int* keys = (unsigned int*)(arena + 16384);    // 16 KB
  unsigned long long* vals =
      (unsigned long long*)(arena + 32768);               // 32 KB
  unsigned long long* sup_sh = (unsigned long long*)(arena + 65536);  // 512 B
  int* prefix = (int*)(arena + 66048);                    // 65 ints
  int* wtot = (int*)(arena + 66308);                      // 4 ints
  int n_wl = *wl_count;
  bool sparse = (n_wl <= WL_LDS_CAP);

  __syncthreads();  // arena reuse barrier
  if (sparse) {
    if (t < 64) sup_sh[t] = 0ull;
    for (int k = t; k < N; k += CF_T) h[k] = 0;
    __syncthreads();
    for (int e = t; e < n_wl; e += CF_T) atomicAdd(&h[wl[e] >> 6], 1);
    __syncthreads();
    // exclusive row prefix: thread owns 8 rows, two-level shfl scan
    int base_r = t * 8;
    int loc[8];
    int s = 0;
#pragma unroll
    for (int k = 0; k < 8; ++k) {
      int r = base_r + k;
      int v = (r < N) ? h[r] : 0;
      loc[k] = s;
      s += v;
    }
    int incl = s;
    for (int d = 1; d < 64; d <<= 1) {
      int v = __shfl_up(incl, d);
      if (lane >= d) incl += v;
    }
    if (lane == 63) wtot[wid] = incl;
    __syncthreads();
    if (wid == 0 && lane < 4) {
      int w = wtot[lane];
      for (int d = 1; d < 4; d <<= 1) {
        int v = __shfl_up(w, d);
        if (lane >= d) w += v;
      }
      wtot[lane] = w;  // inclusive wave totals
    }
    __syncthreads();
    int tbase = (wid ? wtot[wid - 1] : 0) + (incl - s);
#pragma unroll
    for (int k = 0; k < 8; ++k) {
      int r = base_r + k;
      if (r < N) dst[r] = tbase + loc[k];
    }
    __syncthreads();
    for (int e = t; e < n_wl; e += CF_T) {
      unsigned key = wl[e];
      int pos = atomicAdd(&dst[key >> 6], 1);
      keys[pos] = key;
      vals[pos] = mask[(size_t)(key >> 6) * words + (key & 63)];
    }
    __syncthreads();
    if (t < 64) {
      unsigned long long sup = 0ull;
      unsigned long long supg = 0ull;
      int cur_g = -1;
      int chunks = (n_wl + 63) >> 6;
      for (int c = 0; c < chunks; ++c) {
        int idx = (c << 6) + lane;
        unsigned key = (idx < n_wl) ? keys[idx] : 0u;
        unsigned long long val = (idx < n_wl) ? vals[idx] : 0ull;
        int lim = n_wl - (c << 6);
        if (lim > 64) lim = 64;
        for (int e = 0; e < lim; ++e) {
          unsigned k2 = __shfl(key, e);
          unsigned long long v2 = __shfl(val, e);
          int r = k2 >> 6, w = k2 & 63, g = r >> 6;
          if (g != cur_g) {
            supg = __shfl(sup, g);
            cur_g = g;
          }
          bool kept = !((supg >> (r & 63)) & 1ull);
          if (kept) {
            if (lane == w) sup |= v2;
            if (w == g) supg |= v2;
          }
        }
      }
      sup_sh[lane] = (lane < words) ? sup : 0ull;
    }
    __syncthreads();
  } else {
    // dense fallback (rare: worklist overflow)
    if (t < 64) sup_sh[t] = 0ull;
    __syncthreads();
    int rstride = CF_T / words;
    int w2 = t % words;
    int rl0 = t / words;
    for (int g = 0; g < words; ++g) {
      if (wid == 0) {
        int r = g * 64 + lane;
        unsigned long long d = (r < N) ? mask[(size_t)r * words + g] : 0ull;
        unsigned long long supmask = sup_sh[g];
        for (int lp = 0; lp < 64; ++lp) {
          if (!((supmask >> lp) & 1ull)) supmask |= __shfl(d, lp);
        }
        if (lane == 0) sup_sh[g] = supmask;
      }
      __syncthreads();
      unsigned long long supg = sup_sh[g];
      if (w2 > g) {
        unsigned long long acc = 0ull;
        for (int rl = rl0; rl < 64; rl += rstride) {
          if (!((supg >> rl) & 1ull)) {
            int r = g * 64 + rl;
            if (r < N) acc |= mask[(size_t)r * words + w2];
          }
        }
        if (acc) atomicOr(&sup_sh[w2], acc);
      }
      __syncthreads();
    }
  }

  if (t == 0) {
    int acc = 0;
    for (int w = 0; w < words; ++w) {
      prefix[w] = acc;
      int hi = N - w * 64;
      unsigned long long keptw = ~sup_sh[w];
      if (hi < 64) keptw &= (1ull << hi) - 1ull;
      acc += __popcll(keptw);
    }
    prefix[words] = acc;
  }
  __syncthreads();
  int total = prefix[words];
  for (int i = t; i < N; i += CF_T) {
    int w = i >> 6, bb = i & 63;
    if (!((sup_sh[w] >> bb) & 1ull)) {
      int pos = prefix[w] + __popcll(~sup_sh[w] & ((1ull << bb) - 1ull));
      if (pos < topn) out[pos] = order[i];
    }
  }
  for (int k = total + t; k < topn; k += CF_T) out[k] = -1;
}

// =================== fallback path (N > 2048) =============================
__device__ float clip_inter_area_reg(const float* __restrict__ A,
                                     const float* __restrict__ B) {
#pragma clang fp contract(off)
  float Px[8], Py[8], Qx[8], Qy[8];
  for (int k = 0; k < 4; ++k) {
    Px[k] = A[2 * k];
    Py[k] = A[2 * k + 1];
  }
  int cnt = 4;
  for (int e = 0; e < 4; ++e) {
    float ax = B[2 * e], ay = B[2 * e + 1];
    int e2 = (e + 1) & 3;
    float bx = B[2 * e2], by = B[2 * e2 + 1];
    float ex = bx - ax, ey = by - ay;
    int ncnt = 0;
    for (int k = 0; k < cnt; ++k) {
      int kn = (k + 1 < cnt) ? k + 1 : 0;
      float dc = ex * (Py[k] - ay) - ey * (Px[k] - ax);
      float dn = ex * (Py[kn] - ay) - ey * (Px[kn] - ax);
      bool ic = (dc >= 0.0f), inx = (dn >= 0.0f);
      if (ic) {
        if (ncnt < 8) {
          Qx[ncnt] = Px[k];
          Qy[ncnt] = Py[k];
        }
        ++ncnt;
      }
      if (ic != inx) {
        float denom = dc - dn;
        float tp = (fabsf(denom) > 1e-12f) ? (dc / denom) : 0.0f;
        if (ncnt < 8) {
          Qx[ncnt] = Px[k] + tp * (Px[kn] - Px[k]);
          Qy[ncnt] = Py[k] + tp * (Py[kn] - Py[k]);
        }
        ++ncnt;
      }
    }
    cnt = ncnt > 8 ? 8 : ncnt;
    for (int k = 0; k < cnt; ++k) {
      Px[k] = Qx[k];
      Py[k] = Qy[k];
    }
  }
  float area = 0.0f;
  for (int k = 0; k < cnt; ++k) {
    int kn = (k + 1 < cnt) ? k + 1 : 0;
    area += Px[k] * Py[kn] - Px[kn] * Py[k];
  }
  return fmaxf(0.5f * area, 0.0f);
}

__global__ void rank_kernel_fb(const float* __restrict__ scores,
                               int* __restrict__ order, int N) {
  int i = blockIdx.x * blockDim.x + threadIdx.x;
  if (i >= N) return;
  float si = scores[i];
  int r = 0;
  for (int j = 0; j < N; ++j) {
    float sj = scores[j];
    if (sj > si || (sj == si && j < i)) ++r;
  }
  order[r] = i;
}

__global__ void prep_kernel_fb(const float* __restrict__ boxes,
                               const int* __restrict__ order,
                               float* __restrict__ sbox, int N) {
#pragma clang fp contract(off)
  int i = blockIdx.x * blockDim.x + threadIdx.x;
  if (i >= N) return;
  int bx = order[i];
  const float* bp = boxes + 5 * bx;
  float w = bp[2], h = bp[3];
  float* o = sbox + (size_t)i * 12;
  make_corners(bp, o);
  o[8] = bp[0];
  o[9] = bp[1];
  o[10] = 0.5f * sqrtf(w * w + h * h);
  o[11] = w * h;
}

__global__ void iou_direct_kernel(const float* __restrict__ sbox,
                                  unsigned long long* __restrict__ mask, int N,
                                  int words) {
#pragma clang fp contract(off)
  int j = blockIdx.x * blockDim.x + threadIdx.x;
  int i = blockIdx.y;
  if (j >= N || j <= i) return;
  const float* A = sbox + (size_t)i * 12;
  const float* B = sbox + (size_t)j * 12;
  float ddx = B[8] - A[8], ddy = B[9] - A[9];
  float rs = A[10] + B[10];
  if (ddx * ddx + ddy * ddy > rs * rs) return;
  float mn = fminf(A[11], B[11]), mx = fmaxf(A[11], B[11]);
  if (!(mn > 0.699f * mx)) return;
  float inter = clip_inter_area_reg(A, B);
  float uni = A[11] + B[11] - inter;
  float iou = inter / fmaxf(uni, 1e-9f);
  if (iou > 0.7f)
    atomicOr(&mask[(size_t)i * words + (j >> 6)], 1ull << (j & 63));
}

__global__ void __launch_bounds__(1024) nms_sweep_fb(
    const unsigned long long* __restrict__ mask, const int* __restrict__ order,
    int* __restrict__ out, int N, int words, int topn) {
  __shared__ unsigned long long sup[64];
  __shared__ int prefix[65];
  int t = threadIdx.x;
  int lane = t & 63;
  int wave = t >> 6;
  if (t < words) sup[t] = 0ull;
  __syncthreads();
  int rstride = 1024 / words;
  int w2 = t % words;
  int rl0 = t / words;
  for (int g = 0; g < words; ++g) {
    if (wave == 0) {
      int r = g * 64 + lane;
      unsigned long long d = (r < N) ? mask[(size_t)r * words + g] : 0ull;
      unsigned long long supmask = sup[g];
      for (int lp = 0; lp < 64; ++lp) {
        if (!((supmask >> lp) & 1ull)) supmask |= __shfl(d, lp);
      }
      if (lane == 0) sup[g] = supmask;
    }
    __syncthreads();
    unsigned long long supg = sup[g];
    if (w2 > g) {
      unsigned long long acc = 0ull;
      for (int rl = rl0; rl < 64; rl += rstride) {
        if (!((supg >> rl) & 1ull)) {
          int r = g * 64 + rl;
          if (r < N) acc |= mask[(size_t)r * words + w2];
        }
      }
      if (acc) atomicOr(&sup[w2], acc);
    }
    __syncthreads();
  }
  if (t == 0) {
    int acc = 0;
    for (int w = 0; w < words; ++w) {
      prefix[w] = acc;
      int hi = N - w * 64;
      unsigned long long keptw = ~sup[w];
      if (hi < 64) keptw &= (1ull << hi) - 1ull;
      acc += __popcll(keptw);
    }
    prefix[words] = acc;
  }
  __syncthreads();
  int total = prefix[words];
  for (int i = t; i < N; i += 1024) {
    int w = i >> 6, bb = i & 63;
    if (!((sup[w] >> bb) & 1ull)) {
      int pos = prefix[w] + __popcll(~sup[w] & ((1ull << bb) - 1ull));
      if (pos < topn) out[pos] = order[i];
    }
  }
  for (int k = total + t; k < topn; k += 1024) out[k] = -1;
}

extern "C" void kernel_launch(void* const* d_in, const int* in_sizes, int n_in,
                              void* d_out, int out_size, void* d_ws,
                              size_t ws_size, hipStream_t stream) {
  const float* boxes = (const float*)d_in[0];
  const float* scores = (const float*)d_in[1];
  int N = in_sizes[1];
  int words = (N + 63) / 64;

  char* ws = (char*)d_ws;
  size_t off = 0;
  unsigned long long* mask = (unsigned long long*)(ws + off);
  off += (size_t)N * words * sizeof(unsigned long long);
  float4* geo = (float4*)(ws + off);
  off += (size_t)N * sizeof(float4);
  float* corners = (float*)(ws + off);
  off += (size_t)N * 8 * sizeof(float);
  int* order = (int*)(ws + off);
  off += (size_t)N * sizeof(int);
  int* wl_count = (int*)(ws + off);
  int* done = wl_count + 1;
  off += 16;
  unsigned int* wl = (unsigned int*)(ws + off);
  off += (size_t)WL_G_CAP * sizeof(unsigned int);
  float* sbox = (float*)(ws + off);  // fallback only
  off += (size_t)N * 12 * sizeof(float);

  int topn = out_size;
  int* out = (int*)d_out;

  if (N <= 2048) {
    int rb = (N + 7) / 8;
    rank_order<<<rb, 256, 0, stream>>>(boxes, scores, order, geo, corners,
                                       mask, words, wl_count, done, N);
    circle_clip_sweep<<<CF_B, CF_T, 0, stream>>>(corners, order, geo, mask,
                                                 words, wl, wl_count, done,
                                                 out, N, topn);
  } else {
    int nb = (N + 255) / 256;
    hipMemsetAsync(mask, 0, (size_t)N * words * 8, stream);
    rank_kernel_fb<<<nb, 256, 0, stream>>>(scores, order, N);
    prep_kernel_fb<<<nb, 256, 0, stream>>>(boxes, order, sbox, N);
    dim3 grid(nb, N);
    iou_direct_kernel<<<grid, 256, 0, stream>>>(sbox, mask, N, words);
    nms_sweep_fb<<<1, 1024, 0, stream>>>(mask, order, out, N, words, topn);
  }
}

// Round 12
// 81.761 us; speedup vs baseline: 1.3355x; 1.3355x over previous
//
#include <hip/hip_runtime.h>

// Rotated NMS, N boxes [xc,yc,w,h,theta_deg], scores. Output: first 1000 kept
// original indices in score-sorted order, -1 padded. IoU math replicates the
// reference's float32 op order (contract off) — rounds 1-11: absmax 0.
//
// Round 12: revert r11 merge (regressed: last block serializes sweep after
// slowest prefilter block). r10 3-kernel shape + (a) ballot-aggregated
// survivor append, (b) float4 LDS geo staging, (c) sweep fast-chunk path:
// conflict-free 64-entry chunks collapse to one parallel scatter-OR.

#define WL_LDS_CAP 4096
#define WL_G_CAP 65536
#define CF_T 256
#define CF_B 512

// ---------------- K1: rank + order + geo + corners (+ init) ---------------
__device__ __forceinline__ void make_corners(const float* __restrict__ bp,
                                             float* __restrict__ cr) {
#pragma clang fp contract(off)
  float xc = bp[0], yc = bp[1], w = bp[2], h = bp[3], th = bp[4];
  float ang = th * 0.017453292519943295f;
  float c = cosf(ang), sn = sinf(ang);
  float dx = w * 0.5f, dy = h * 0.5f;
  const float lx[4] = {-dx, dx, dx, -dx};
  const float ly[4] = {-dy, -dy, dy, dy};
#pragma unroll
  for (int k = 0; k < 4; ++k) {
    cr[2 * k] = xc + lx[k] * c - ly[k] * sn;  // no FMA: match reference
    cr[2 * k + 1] = yc + lx[k] * sn + ly[k] * c;
  }
}

__global__ void __launch_bounds__(256) rank_order(
    const float* __restrict__ boxes, const float* __restrict__ scores,
    int* __restrict__ order, float4* __restrict__ geo,
    float* __restrict__ corners, unsigned long long* __restrict__ mask,
    int words, int* __restrict__ wl_count, int N) {
#pragma clang fp contract(off)
  __shared__ float s[2048];
  int t = threadIdx.x;
  int gtid = blockIdx.x * 256 + t;
  if (gtid == 0) *wl_count = 0;
  size_t mtot = (size_t)N * words;
  for (size_t k = gtid; k < mtot; k += (size_t)gridDim.x * 256) mask[k] = 0ull;
  for (int k = t; k < N; k += 256) s[k] = scores[k];
  __syncthreads();
  int il = t >> 5, jc = t & 31;
  int i = blockIdx.x * 8 + il;
  int r = 0;
  if (i < N) {
    float si = s[i];
#pragma unroll 8
    for (int j = jc; j < N; j += 32) {
      float a = s[j];
      r += (a > si) || (a == si && j < i);
    }
  }
  r += __shfl_xor(r, 1);
  r += __shfl_xor(r, 2);
  r += __shfl_xor(r, 4);
  r += __shfl_xor(r, 8);
  r += __shfl_xor(r, 16);
  if (i < N && jc == 0) {
    order[r] = i;
    const float* bp = boxes + 5 * i;
    float w = bp[2], h = bp[3];
    float4 g;
    g.x = bp[0];
    g.y = bp[1];
    g.z = 0.5f * sqrtf(w * w + h * h);  // bounding-circle radius
    g.w = w * h;                        // area
    geo[r] = g;
    float cr[8];
    make_corners(bp, cr);
    float4* c4 = (float4*)(corners + 8 * r);
    c4[0] = make_float4(cr[0], cr[1], cr[2], cr[3]);
    c4[1] = make_float4(cr[4], cr[5], cr[6], cr[7]);
  }
}

// Exact SH clip, polygon in per-thread LDS slot (lane-major, conflict-free).
#define PIDX(bu, xy, v) ((((bu) * 2 + (xy)) * 8 + (v)) * CF_T + (t))
__device__ float clip_poly_lds(float* __restrict__ poly, int t,
                               const float* __restrict__ CA,
                               const float* __restrict__ CB) {
#pragma clang fp contract(off)
#pragma unroll
  for (int k = 0; k < 4; ++k) {
    poly[PIDX(0, 0, k)] = CA[2 * k];
    poly[PIDX(0, 1, k)] = CA[2 * k + 1];
  }
  int cnt = 4, cur = 0;
  for (int e = 0; e < 4; ++e) {
    float ax = CB[2 * e], ay = CB[2 * e + 1];
    int e2 = (e + 1) & 3;
    float bx = CB[2 * e2], by = CB[2 * e2 + 1];
    float ex = bx - ax, ey = by - ay;
    int nxtb = cur ^ 1;
    int ncnt = 0;
    for (int k = 0; k < cnt; ++k) {
      int kn = (k + 1 < cnt) ? k + 1 : 0;
      float px = poly[PIDX(cur, 0, k)], py = poly[PIDX(cur, 1, k)];
      float nx = poly[PIDX(cur, 0, kn)], ny = poly[PIDX(cur, 1, kn)];
      float dc = ex * (py - ay) - ey * (px - ax);
      float dn = ex * (ny - ay) - ey * (nx - ax);
      bool ic = (dc >= 0.0f), inx = (dn >= 0.0f);
      if (ic) {
        if (ncnt < 8) {
          poly[PIDX(nxtb, 0, ncnt)] = px;
          poly[PIDX(nxtb, 1, ncnt)] = py;
        }
        ++ncnt;
      }
      if (ic != inx) {
        float denom = dc - dn;
        float tp = (fabsf(denom) > 1e-12f) ? (dc / denom) : 0.0f;
        if (ncnt < 8) {
          poly[PIDX(nxtb, 0, ncnt)] = px + tp * (nx - px);
          poly[PIDX(nxtb, 1, ncnt)] = py + tp * (ny - py);
        }
        ++ncnt;
      }
    }
    cnt = ncnt > 8 ? 8 : ncnt;
    cur = nxtb;
  }
  float area = 0.0f;
  for (int k = 0; k < cnt; ++k) {
    int kn = (k + 1 < cnt) ? k + 1 : 0;
    area += poly[PIDX(cur, 0, k)] * poly[PIDX(cur, 1, kn)] -
            poly[PIDX(cur, 0, kn)] * poly[PIDX(cur, 1, k)];
  }
  return fmaxf(0.5f * area, 0.0f);
}

__device__ __forceinline__ void emit_pair(float inter, float ai, float aj,
                                          int i, int j,
                                          unsigned long long* __restrict__ mask,
                                          int words,
                                          unsigned int* __restrict__ wl,
                                          int* __restrict__ wl_count) {
#pragma clang fp contract(off)
  float uni = ai + aj - inter;
  float iou = inter / fmaxf(uni, 1e-9f);
  if (iou > 0.7f) {
    unsigned long long old =
        atomicOr(&mask[(size_t)i * words + (j >> 6)], 1ull << (j & 63));
    if (old == 0ull) {
      int x = atomicAdd(wl_count, 1);
      if (x < WL_G_CAP) wl[x] = ((unsigned)i << 6) | (unsigned)(j >> 6);
    }
  }
}

// ---------------- K2: circle+area prefilter + exact clip ------------------
// LDS: geoS 32K | buf 8K | poly 32K = 72K -> 2 blocks/CU.
__global__ void __launch_bounds__(CF_T) circle_clip(
    const float* __restrict__ corners, const float4* __restrict__ geo,
    unsigned long long* __restrict__ mask, int words,
    unsigned int* __restrict__ wl, int* __restrict__ wl_count, int N) {
#pragma clang fp contract(off)
  __shared__ float4 geoS[2048];       // 32 KB
  __shared__ unsigned int buf[2048];  // 8 KB
  __shared__ float poly[2 * 2 * 8 * CF_T];  // 32 KB
  __shared__ int bcnt;
  int t = threadIdx.x;
  int lane = t & 63;
  if (t == 0) bcnt = 0;
  for (int k = t; k < N; k += CF_T) geoS[k] = geo[k];
  __syncthreads();

  int nrows = (N + 1) >> 1;  // process row-pairs {i, N-1-i}
  for (int rp = blockIdx.x; rp < nrows; rp += gridDim.x) {
    for (int q = 0; q < 2; ++q) {
      int i = q ? (N - 1 - rp) : rp;
      if (q && i == rp) break;  // odd-N middle row once
      float4 gi = geoS[i];
      int jbase = i + 1;
      int iters = (N - jbase + CF_T - 1) / CF_T;
      for (int it = 0; it < iters; ++it) {
        int j = jbase + it * CF_T + t;
        bool keep = false;
        if (j < N) {
          float4 gj = geoS[j];
          float ddx = gj.x - gi.x, ddy = gj.y - gi.y;
          float rs = gi.z + gj.z;
          float mn = fminf(gi.w, gj.w), mx = fmaxf(gi.w, gj.w);
          // IoU <= min/(A+B-min): IoU>0.7 requires mn>0.7*mx (0.699 margin)
          keep = (ddx * ddx + ddy * ddy <= rs * rs) && (mn > 0.699f * mx);
        }
        unsigned long long ball = __ballot(keep);
        if (ball) {  // one LDS atomic per wave-iteration (was per lane)
          int base = 0;
          if (lane == 0) base = atomicAdd(&bcnt, __popcll(ball));
          base = __shfl(base, 0);
          if (keep) {
            int idx = base + __popcll(ball & ((1ull << lane) - 1ull));
            if (idx < 2048) {
              buf[idx] = ((unsigned)i << 16) | (unsigned)j;
            } else {  // overflow (adversarial only): inline clip
              float CA[8], CB[8];
              *(float4*)(CA) = ((const float4*)(corners + 8 * i))[0];
              *(float4*)(CA + 4) = ((const float4*)(corners + 8 * i))[1];
              *(float4*)(CB) = ((const float4*)(corners + 8 * j))[0];
              *(float4*)(CB + 4) = ((const float4*)(corners + 8 * j))[1];
              float inter = clip_poly_lds(poly, t, CA, CB);
              emit_pair(inter, gi.w, geoS[j].w, i, j, mask, words, wl,
                        wl_count);
            }
          }
        }
      }
    }
  }
  __syncthreads();
  int n2 = bcnt < 2048 ? bcnt : 2048;
  for (int p = t; p < n2; p += CF_T) {
    unsigned int pk = buf[p];
    int i = pk >> 16, j = pk & 0xFFFF;
    float CA[8], CB[8];
    *(float4*)(CA) = ((const float4*)(corners + 8 * i))[0];
    *(float4*)(CA + 4) = ((const float4*)(corners + 8 * i))[1];
    *(float4*)(CB) = ((const float4*)(corners + 8 * j))[0];
    *(float4*)(CB + 4) = ((const float4*)(corners + 8 * j))[1];
    float inter = clip_poly_lds(poly, t, CA, CB);
    emit_pair(inter, geoS[i].w, geoS[j].w, i, j, mask, words, wl, wl_count);
  }
}

// ---------------- K3: greedy sweep (sparse + fast-chunk path) -------------
__global__ void __launch_bounds__(1024) nms_sweep(
    const unsigned long long* __restrict__ mask, const int* __restrict__ order,
    const unsigned int* __restrict__ wl, const int* __restrict__ wl_count,
    int* __restrict__ out, int N, int words, int topn) {
  __shared__ unsigned long long sup_sh[64];
  __shared__ int prefix[65];
  __shared__ int h[2048], dst[2048];
  __shared__ int wtot[16];
  __shared__ unsigned int keys[WL_LDS_CAP];
  __shared__ unsigned long long vals[WL_LDS_CAP];  // 32 KB
  __shared__ unsigned long long tmp64[64];
  int t = threadIdx.x;
  int lane = t & 63;
  int wid = t >> 6;
  int n_wl = *wl_count;
  bool sparse = (words <= 32) && (N <= 2048) && (n_wl <= WL_LDS_CAP);

  if (sparse) {
    if (t < 64) sup_sh[t] = 0ull;
    for (int k = t; k < N; k += 1024) h[k] = 0;
    __syncthreads();
    unsigned lk[WL_LDS_CAP / 1024];
    unsigned long long lv[WL_LDS_CAP / 1024];
    int ne = 0;
    for (int e = t; e < n_wl; e += 1024) {
      unsigned key = wl[e];
      lk[ne] = key;
      lv[ne] = mask[(size_t)(key >> 6) * words + (key & 63)];
      atomicAdd(&h[key >> 6], 1);
      ++ne;
    }
    __syncthreads();
    int a = (2 * t < N) ? h[2 * t] : 0;
    int b = (2 * t + 1 < N) ? h[2 * t + 1] : 0;
    int s = a + b;
    for (int d = 1; d < 64; d <<= 1) {
      int v = __shfl_up(s, d);
      if (lane >= d) s += v;
    }
    if (lane == 63) wtot[wid] = s;
    __syncthreads();
    if (wid == 0) {
      int w = (lane < 16) ? wtot[lane] : 0;
      for (int d = 1; d < 16; d <<= 1) {
        int v = __shfl_up(w, d);
        if (lane >= d) w += v;
      }
      if (lane < 16) wtot[lane] = w;
    }
    __syncthreads();
    int base = (wid ? wtot[wid - 1] : 0) + (s - (a + b));
    if (2 * t < N) dst[2 * t] = base;
    if (2 * t + 1 < N) dst[2 * t + 1] = base + a;
    __syncthreads();
    for (int ii = 0; ii < ne; ++ii) {
      int pos = atomicAdd(&dst[lk[ii] >> 6], 1);
      keys[pos] = lk[ii];
      vals[pos] = lv[ii];
    }
    __syncthreads();
    if (t < 64) {
      unsigned long long sup = 0ull;
      int chunks = (n_wl + 63) >> 6;
      for (int c = 0; c < chunks; ++c) {
        int idx = (c << 6) + lane;
        int lim = n_wl - (c << 6);
        if (lim > 64) lim = 64;
        unsigned key = (idx < n_wl) ? keys[idx] : 0u;
        unsigned long long val = (idx < n_wl) ? vals[idx] : 0ull;
        // conflict = some entry's val touches rows [rmin,rmax] of this chunk
        int rmin = (int)(__shfl(key, 0) >> 6);
        int rmax = (int)(__shfl(key, lim - 1) >> 6);
        bool conflict = false;
        if (lane < lim) {
          int w = key & 63;
          int wlo = w << 6;
          int lo = rmin > wlo ? rmin : wlo;
          int hi = rmax < wlo + 63 ? rmax : wlo + 63;
          if (lo <= hi) {
            int nb = hi - lo + 1;
            unsigned long long rm =
                (nb >= 64) ? ~0ull : (((1ull << nb) - 1ull) << (lo - wlo));
            conflict = (val & rm) != 0ull;
          }
        }
        if (__ballot(conflict) == 0ull) {
          // fast path: kept-bits fixed by pre-chunk sup; parallel scatter-OR
          int r = (int)(key >> 6), g = r >> 6;
          unsigned long long supg = __shfl(sup, g);
          bool kept = (lane < lim) && !((supg >> (r & 63)) & 1ull);
          tmp64[lane] = 0ull;
          __asm__ volatile("s_waitcnt lgkmcnt(0)" ::: "memory");
          if (kept) {
            unsigned* tp = (unsigned*)&tmp64[key & 63];
            unsigned lo32 = (unsigned)val, hi32 = (unsigned)(val >> 32);
            if (lo32) atomicOr(&tp[0], lo32);
            if (hi32) atomicOr(&tp[1], hi32);
          }
          __asm__ volatile("s_waitcnt lgkmcnt(0)" ::: "memory");
          sup |= tmp64[lane];
        } else {
          // exact serial fallback
          unsigned long long supg = 0ull;
          int cur_g = -1;
          for (int e = 0; e < lim; ++e) {
            unsigned k2 = __shfl(key, e);
            unsigned long long v2 = __shfl(val, e);
            int r2 = (int)(k2 >> 6), w2 = (int)(k2 & 63), g2 = r2 >> 6;
            if (g2 != cur_g) {
              supg = __shfl(sup, g2);
              cur_g = g2;
            }
            bool kept = !((supg >> (r2 & 63)) & 1ull);
            if (kept) {
              if (lane == w2) sup |= v2;
              if (w2 == g2) supg |= v2;
            }
          }
        }
      }
      sup_sh[lane] = (lane < words) ? sup : 0ull;
    }
    __syncthreads();
  } else {
    if (t < 64) sup_sh[t] = 0ull;
    __syncthreads();
    int rstride = 1024 / words;
    int w2 = t % words;
    int rl0 = t / words;
    for (int g = 0; g < words; ++g) {
      if (wid == 0) {
        int r = g * 64 + lane;
        unsigned long long d = (r < N) ? mask[(size_t)r * words + g] : 0ull;
        unsigned long long supmask = sup_sh[g];
        for (int lp = 0; lp < 64; ++lp) {
          if (!((supmask >> lp) & 1ull)) supmask |= __shfl(d, lp);
        }
        if (lane == 0) sup_sh[g] = supmask;
      }
      __syncthreads();
      unsigned long long supg = sup_sh[g];
      if (w2 > g) {
        unsigned long long acc = 0ull;
        for (int rl = rl0; rl < 64; rl += rstride) {
          if (!((supg >> rl) & 1ull)) {
            int r = g * 64 + rl;
            if (r < N) acc |= mask[(size_t)r * words + w2];
          }
        }
        if (acc) atomicOr(&sup_sh[w2], acc);
      }
      __syncthreads();
    }
  }

  if (t == 0) {
    int acc = 0;
    for (int w = 0; w < words; ++w) {
      prefix[w] = acc;
      int hi = N - w * 64;
      unsigned long long keptw = ~sup_sh[w];
      if (hi < 64) keptw &= (1ull << hi) - 1ull;
      acc += __popcll(keptw);
    }
    prefix[words] = acc;
  }
  __syncthreads();
  int total = prefix[words];
  for (int i = t; i < N; i += 1024) {
    int w = i >> 6, bb = i & 63;
    if (!((sup_sh[w] >> bb) & 1ull)) {
      int pos = prefix[w] + __popcll(~sup_sh[w] & ((1ull << bb) - 1ull));
      if (pos < topn) out[pos] = order[i];
    }
  }
  for (int k = total + t; k < topn; k += 1024) out[k] = -1;
}

// =================== fallback path (N > 2048) =============================
__device__ float clip_inter_area_reg(const float* __restrict__ A,
                                     const float* __restrict__ B) {
#pragma clang fp contract(off)
  float Px[8], Py[8], Qx[8], Qy[8];
  for (int k = 0; k < 4; ++k) {
    Px[k] = A[2 * k];
    Py[k] = A[2 * k + 1];
  }
  int cnt = 4;
  for (int e = 0; e < 4; ++e) {
    float ax = B[2 * e], ay = B[2 * e + 1];
    int e2 = (e + 1) & 3;
    float bx = B[2 * e2], by = B[2 * e2 + 1];
    float ex = bx - ax, ey = by - ay;
    int ncnt = 0;
    for (int k = 0; k < cnt; ++k) {
      int kn = (k + 1 < cnt) ? k + 1 : 0;
      float dc = ex * (Py[k] - ay) - ey * (Px[k] - ax);
      float dn = ex * (Py[kn] - ay) - ey * (Px[kn] - ax);
      bool ic = (dc >= 0.0f), inx = (dn >= 0.0f);
      if (ic) {
        if (ncnt < 8) {
          Qx[ncnt] = Px[k];
          Qy[ncnt] = Py[k];
        }
        ++ncnt;
      }
      if (ic != inx) {
        float denom = dc - dn;
        float tp = (fabsf(denom) > 1e-12f) ? (dc / denom) : 0.0f;
        if (ncnt < 8) {
          Qx[ncnt] = Px[k] + tp * (Px[kn] - Px[k]);
          Qy[ncnt] = Py[k] + tp * (Py[kn] - Py[k]);
        }
        ++ncnt;
      }
    }
    cnt = ncnt > 8 ? 8 : ncnt;
    for (int k = 0; k < cnt; ++k) {
      Px[k] = Qx[k];
      Py[k] = Qy[k];
    }
  }
  float area = 0.0f;
  for (int k = 0; k < cnt; ++k) {
    int kn = (k + 1 < cnt) ? k + 1 : 0;
    area += Px[k] * Py[kn] - Px[kn] * Py[k];
  }
  return fmaxf(0.5f * area, 0.0f);
}

__global__ void rank_kernel_fb(const float* __restrict__ scores,
                               int* __restrict__ order, int N) {
  int i = blockIdx.x * blockDim.x + threadIdx.x;
  if (i >= N) return;
  float si = scores[i];
  int r = 0;
  for (int j = 0; j < N; ++j) {
    float sj = scores[j];
    if (sj > si || (sj == si && j < i)) ++r;
  }
  order[r] = i;
}

__global__ void prep_kernel_fb(const float* __restrict__ boxes,
                               const int* __restrict__ order,
                               float* __restrict__ sbox, int N) {
#pragma clang fp contract(off)
  int i = blockIdx.x * blockDim.x + threadIdx.x;
  if (i >= N) return;
  int bx = order[i];
  const float* bp = boxes + 5 * bx;
  float w = bp[2], h = bp[3];
  float* o = sbox + (size_t)i * 12;
  make_corners(bp, o);
  o[8] = bp[0];
  o[9] = bp[1];
  o[10] = 0.5f * sqrtf(w * w + h * h);
  o[11] = w * h;
}

__global__ void iou_direct_kernel(const float* __restrict__ sbox,
                                  unsigned long long* __restrict__ mask, int N,
                                  int words) {
#pragma clang fp contract(off)
  int j = blockIdx.x * blockDim.x + threadIdx.x;
  int i = blockIdx.y;
  if (j >= N || j <= i) return;
  const float* A = sbox + (size_t)i * 12;
  const float* B = sbox + (size_t)j * 12;
  float ddx = B[8] - A[8], ddy = B[9] - A[9];
  float rs = A[10] + B[10];
  if (ddx * ddx + ddy * ddy > rs * rs) return;
  float mn = fminf(A[11], B[11]), mx = fmaxf(A[11], B[11]);
  if (!(mn > 0.699f * mx)) return;
  float inter = clip_inter_area_reg(A, B);
  float uni = A[11] + B[11] - inter;
  float iou = inter / fmaxf(uni, 1e-9f);
  if (iou > 0.7f)
    atomicOr(&mask[(size_t)i * words + (j >> 6)], 1ull << (j & 63));
}

__global__ void __launch_bounds__(1024) nms_sweep_fb(
    const unsigned long long* __restrict__ mask, const int* __restrict__ order,
    int* __restrict__ out, int N, int words, int topn) {
  __shared__ unsigned long long sup[64];
  __shared__ int prefix[65];
  int t = threadIdx.x;
  int lane = t & 63;
  int wave = t >> 6;
  if (t < words) sup[t] = 0ull;
  __syncthreads();
  int rstride = 1024 / words;
  int w2 = t % words;
  int rl0 = t / words;
  for (int g = 0; g < words; ++g) {
    if (wave == 0) {
      int r = g * 64 + lane;
      unsigned long long d = (r < N) ? mask[(size_t)r * words + g] : 0ull;
      unsigned long long supmask = sup[g];
      for (int lp = 0; lp < 64; ++lp) {
        if (!((supmask >> lp) & 1ull)) supmask |= __shfl(d, lp);
      }
      if (lane == 0) sup[g] = supmask;
    }
    __syncthreads();
    unsigned long long supg = sup[g];
    if (w2 > g) {
      unsigned long long acc = 0ull;
      for (int rl = rl0; rl < 64; rl += rstride) {
        if (!((supg >> rl) & 1ull)) {
          int r = g * 64 + rl;
          if (r < N) acc |= mask[(size_t)r * words + w2];
        }
      }
      if (acc) atomicOr(&sup[w2], acc);
    }
    __syncthreads();
  }
  if (t == 0) {
    int acc = 0;
    for (int w = 0; w < words; ++w) {
      prefix[w] = acc;
      int hi = N - w * 64;
      unsigned long long keptw = ~sup[w];
      if (hi < 64) keptw &= (1ull << hi) - 1ull;
      acc += __popcll(keptw);
    }
    prefix[words] = acc;
  }
  __syncthreads();
  int total = prefix[words];
  for (int i = t; i < N; i += 1024) {
    int w = i >> 6, bb = i & 63;
    if (!((sup[w] >> bb) & 1ull)) {
      int pos = prefix[w] + __popcll(~sup[w] & ((1ull << bb) - 1ull));
      if (pos < topn) out[pos] = order[i];
    }
  }
  for (int k = total + t; k < topn; k += 1024) out[k] = -1;
}

extern "C" void kernel_launch(void* const* d_in, const int* in_sizes, int n_in,
                              void* d_out, int out_size, void* d_ws,
                              size_t ws_size, hipStream_t stream) {
  const float* boxes = (const float*)d_in[0];
  const float* scores = (const float*)d_in[1];
  int N = in_sizes[1];
  int words = (N + 63) / 64;

  char* ws = (char*)d_ws;
  size_t off = 0;
  unsigned long long* mask = (unsigned long long*)(ws + off);
  off += (size_t)N * words * sizeof(unsigned long long);
  float4* geo = (float4*)(ws + off);
  off += (size_t)N * sizeof(float4);
  float* corners = (float*)(ws + off);
  off += (size_t)N * 8 * sizeof(float);
  int* order = (int*)(ws + off);
  off += (size_t)N * sizeof(int);
  int* wl_count = (int*)(ws + off);
  off += 16;
  unsigned int* wl = (unsigned int*)(ws + off);
  off += (size_t)WL_G_CAP * sizeof(unsigned int);
  float* sbox = (float*)(ws + off);  // fallback only
  off += (size_t)N * 12 * sizeof(float);

  int topn = out_size;
  int* out = (int*)d_out;

  if (N <= 2048) {
    int rb = (N + 7) / 8;
    rank_order<<<rb, 256, 0, stream>>>(boxes, scores, order, geo, corners,
                                       mask, words, wl_count, N);
    circle_clip<<<CF_B, CF_T, 0, stream>>>(corners, geo, mask, words, wl,
                                           wl_count, N);
    nms_sweep<<<1, 1024, 0, stream>>>(mask, order, wl, wl_count, out, N, words,
                                      topn);
  } else {
    int nb = (N + 255) / 256;
    hipMemsetAsync(mask, 0, (size_t)N * words * 8, stream);
    rank_kernel_fb<<<nb, 256, 0, stream>>>(scores, order, N);
    prep_kernel_fb<<<nb, 256, 0, stream>>>(boxes, order, sbox, N);
    dim3 grid(nb, N);
    iou_direct_kernel<<<grid, 256, 0, stream>>>(sbox, mask, N, words);
    nms_sweep_fb<<<1, 1024, 0, stream>>>(mask, order, out, N, words, topn);
  }
}